// Round 2
// baseline (12065.141 us; speedup 1.0000x reference)
//
#include <hip/hip_runtime.h>
#include <math.h>

#define VOCAB 10000
#define DIM 64
#define LTOK 8
#define DGPT 256
#define NHEAD 4
#define NNODES 8192
#define NEDGES 2048
#define FDIM 512                 // LTOK*DIM
#define NROWS (NEDGES*LTOK)      // 16384

// ---------------- mask / labels ----------------
__global__ __launch_bounds__(256) void k_mask(const int* __restrict__ etok,
                                              const int* __restrict__ mrows,
                                              float* __restrict__ labels,
                                              int* __restrict__ mtok) {
    int i = blockIdx.x * 256 + threadIdx.x;     // < 16384
    int e = i >> 3;
    int t = etok[i];
    bool m = (mrows[e] != 0) && (t > 3);        // SPECIAL = {0,1,2,3}
    labels[i] = m ? (float)t : -100.0f;
    mtok[i] = m ? 4 : t;                        // MASK_ID = 4
}

// ---------------- embedding gather ----------------
__global__ __launch_bounds__(256) void k_embed(const int* __restrict__ tok,
                                               const float* __restrict__ emb,
                                               float* __restrict__ outf, int total) {
    int i = blockIdx.x * 256 + threadIdx.x;
    if (i >= total) return;
    int d = i & 63;
    int tl = i >> 6;
    outf[i] = emb[(size_t)tok[tl] * DIM + d];
}

// ---------------- eh = h[src] + h[dst] ----------------
__global__ __launch_bounds__(256) void k_eh(const float* __restrict__ h,
                                            const int* __restrict__ src,
                                            const int* __restrict__ dst,
                                            float* __restrict__ eh) {
    int i = blockIdx.x * 256 + threadIdx.x;     // < 2048*512
    int e = i >> 9; int f = i & 511;
    eh[i] = h[(size_t)src[e] * FDIM + f] + h[(size_t)dst[e] * FDIM + f];
}

// ---------------- generic tiled fp32 GEMM with fused epilogue ----------------
// out[M,N] = act(A[M,K] @ W[K,N] + bias[N] + res[resRow,N]) ; optional atomic scatter by dstIdx
// act: 0 none, 1 relu, 2 gelu(tanh approx)
__global__ __launch_bounds__(256) void gemm_kernel(
    const float* __restrict__ A, const float* __restrict__ W,
    const float* __restrict__ bias, const float* __restrict__ res,
    const int* __restrict__ resIdx, const int* __restrict__ dstIdx,
    float* __restrict__ out, int M, int N, int K, int act)
{
    __shared__ float As[16][68];   // [k][row] (+pad)
    __shared__ float Ws[16][68];   // [k][col] (+pad)
    int tid = threadIdx.x;
    int row0 = blockIdx.x * 64, col0 = blockIdx.y * 64;
    int ty = tid >> 4, tx = tid & 15;
    float acc[4][4] = {};
    int arow = tid >> 2;            // 0..63
    int acol4 = (tid & 3) * 4;      // 0,4,8,12
    int wrow = tid >> 4;            // 0..15
    int wcol4 = (tid & 15) * 4;

    for (int kc = 0; kc < K; kc += 16) {
        float4 av = *(const float4*)&A[(size_t)(row0 + arow) * K + kc + acol4];
        float4 wv = *(const float4*)&W[(size_t)(kc + wrow) * N + col0 + wcol4];
        __syncthreads();
        As[acol4 + 0][arow] = av.x;
        As[acol4 + 1][arow] = av.y;
        As[acol4 + 2][arow] = av.z;
        As[acol4 + 3][arow] = av.w;
        *(float4*)&Ws[wrow][wcol4] = wv;
        __syncthreads();
#pragma unroll
        for (int kk = 0; kk < 16; kk++) {
            float4 a4 = *(const float4*)&As[kk][ty * 4];
            float4 w4 = *(const float4*)&Ws[kk][tx * 4];
            float ar[4] = {a4.x, a4.y, a4.z, a4.w};
            float wr[4] = {w4.x, w4.y, w4.z, w4.w};
#pragma unroll
            for (int i = 0; i < 4; i++)
#pragma unroll
                for (int j = 0; j < 4; j++)
                    acc[i][j] += ar[i] * wr[j];
        }
    }

    const float c0 = 0.7978845608028654f, c1 = 0.044715f;
#pragma unroll
    for (int i = 0; i < 4; i++) {
        int row = row0 + ty * 4 + i;
        int rrow = resIdx ? resIdx[row] : row;
#pragma unroll
        for (int j = 0; j < 4; j++) {
            int col = col0 + tx * 4 + j;
            float v = acc[i][j];
            if (bias) v += bias[col];
            if (res)  v += res[(size_t)rrow * N + col];
            if (act == 1) v = fmaxf(v, 0.0f);
            else if (act == 2) { float t = v; v = 0.5f * t * (1.0f + tanhf(c0 * (t + c1 * t * t * t))); }
            if (dstIdx) atomicAdd(&out[(size_t)dstIdx[row] * N + col], v);
            else out[(size_t)row * N + col] = v;
        }
    }
}

// ---------------- per-edge attention (S=8, NH=4, hd=64) ----------------
__global__ __launch_bounds__(256) void k_attn(const float* __restrict__ q,
                                              const float* __restrict__ k,
                                              const float* __restrict__ v,
                                              float* __restrict__ o) {
    __shared__ float qs[8 * 256], ks[8 * 256], vs[8 * 256];
    __shared__ float sc[4 * 8 * 8];
    int b = blockIdx.x, t = threadIdx.x;
    const size_t base = (size_t)b * (8 * 256);
    for (int i = t; i < 2048; i += 256) { qs[i] = q[base + i]; ks[i] = k[base + i]; vs[i] = v[base + i]; }
    __syncthreads();
    {
        int h = t >> 6, sq = (t >> 3) & 7, sk = t & 7;
        float acc = 0.0f;
#pragma unroll
        for (int d = 0; d < 64; d++) acc += qs[sq * 256 + h * 64 + d] * ks[sk * 256 + h * 64 + d];
        sc[t] = acc * 0.125f;     // 1/sqrt(64)
    }
    __syncthreads();
    if (t < 32) {
        int h = t >> 3, sq = t & 7;
        float* r = &sc[h * 64 + sq * 8];
        float M = r[0];
        for (int i = 1; i < 8; i++) M = fmaxf(M, r[i]);
        float S = 0.0f, ex[8];
        for (int i = 0; i < 8; i++) { ex[i] = __expf(r[i] - M); S += ex[i]; }
        float inv = 1.0f / S;
        for (int i = 0; i < 8; i++) r[i] = ex[i] * inv;
    }
    __syncthreads();
    {
        int col = t; int h = col >> 6;
#pragma unroll
        for (int sq = 0; sq < 8; sq++) {
            float a = 0.0f;
#pragma unroll
            for (int sk = 0; sk < 8; sk++) a += sc[h * 64 + sq * 8 + sk] * vs[sk * 256 + col];
            o[base + sq * 256 + col] = a;
        }
    }
}

// ---------------- lm_head (tied emb) + online softmax, recompute pass ----------------
__global__ __launch_bounds__(256) void k_lmhead(const float* __restrict__ y,
                                                const float* __restrict__ emb,
                                                float* __restrict__ probs) {
    int t = threadIdx.x;
    int rloc = t >> 4;                 // 16 rows/block
    int c = t & 15;                    // 16 threads/row
    int row = blockIdx.x * 16 + rloc;
    float yr[64];
    const float4* yp = (const float4*)&y[(size_t)row * 64];
#pragma unroll
    for (int i = 0; i < 16; i++) { float4 v4 = yp[i]; yr[4*i]=v4.x; yr[4*i+1]=v4.y; yr[4*i+2]=v4.z; yr[4*i+3]=v4.w; }

    float m = -1e30f, s = 0.0f;
    for (int j = 0; j < VOCAB / 16; j++) {
        int v = c + 16 * j;
        const float4* ep = (const float4*)&emb[(size_t)v * 64];
        float acc = 0.0f;
#pragma unroll
        for (int i = 0; i < 16; i++) {
            float4 e4 = ep[i];
            acc += yr[4*i] * e4.x + yr[4*i+1] * e4.y + yr[4*i+2] * e4.z + yr[4*i+3] * e4.w;
        }
        float nm = fmaxf(m, acc);
        s = s * __expf(m - nm) + __expf(acc - nm);
        m = nm;
    }
    __shared__ float ms[256], ss[256], rowm[16], rowsi[16];
    ms[t] = m; ss[t] = s;
    __syncthreads();
    if (c == 0) {
        float M = -1e30f;
        for (int q = 0; q < 16; q++) M = fmaxf(M, ms[rloc * 16 + q]);
        float S = 0.0f;
        for (int q = 0; q < 16; q++) S += ss[rloc * 16 + q] * __expf(ms[rloc * 16 + q] - M);
        rowm[rloc] = M; rowsi[rloc] = 1.0f / S;
    }
    __syncthreads();
    float M = rowm[rloc], Sinv = rowsi[rloc];
    float* prow = &probs[(size_t)row * VOCAB];
    for (int j = 0; j < VOCAB / 16; j++) {
        int v = c + 16 * j;
        const float4* ep = (const float4*)&emb[(size_t)v * 64];
        float acc = 0.0f;
#pragma unroll
        for (int i = 0; i < 16; i++) {
            float4 e4 = ep[i];
            acc += yr[4*i] * e4.x + yr[4*i+1] * e4.y + yr[4*i+2] * e4.z + yr[4*i+3] * e4.w;
        }
        prow[v] = __expf(acc - M) * Sinv;
    }
}

extern "C" void kernel_launch(void* const* d_in, const int* in_sizes, int n_in,
                              void* d_out, int out_size, void* d_ws, size_t ws_size,
                              hipStream_t stream) {
    const int* node_tokens = (const int*)d_in[0];
    const int* edge_tokens = (const int*)d_in[1];
    const int* edge_index  = (const int*)d_in[2];
    const int* mask_rows   = (const int*)d_in[3];   // bool passed as int32
    const float* emb    = (const float*)d_in[4];
    const float* W_msg  = (const float*)d_in[5];
    const float* W_node = (const float*)d_in[6];
    const float* lc1_w  = (const float*)d_in[7];
    const float* lc1_b  = (const float*)d_in[8];
    const float* lc2_w  = (const float*)d_in[9];
    const float* lc2_b  = (const float*)d_in[10];
    const float* Wq     = (const float*)d_in[11];
    const float* Wk     = (const float*)d_in[12];
    const float* Wv     = (const float*)d_in[13];
    const float* Wo     = (const float*)d_in[14];
    const float* Wf1    = (const float*)d_in[15];
    const float* Wf2    = (const float*)d_in[16];

    const int* src = edge_index;
    const int* dst = edge_index + NEDGES;

    float* labels = (float*)d_out;
    float* probs  = labels + NROWS;

    float* ws = (float*)d_ws;
    float* X   = ws;                  // [8192,512]
    float* E_  = X   + 4194304;       // [2048,512]
    float* AGG = E_  + 1048576;       // [8192,512], becomes H in-place
    float* EH  = AGG + 4194304;       // [2048,512] == z rows [16384,64]
    float* Z1  = EH  + 1048576;       // [16384,256]
    float* Q_  = Z1  + 4194304;
    float* K_  = Q_  + 4194304;
    float* Vv  = K_  + 4194304;
    float* O_  = Vv  + 4194304;
    float* X2  = O_  + 4194304;
    float* U_  = X2  + 4194304;       // [16384,1024]
    float* Y2  = U_  + 16777216;      // [16384,256]
    float* Y_  = Y2  + 4194304;       // [16384,64]
    int*  MTOK = (int*)(Y_ + 1048576);

    // zero agg for scatter-add
    hipMemsetAsync(AGG, 0, (size_t)NNODES * FDIM * sizeof(float), stream);

    // masking + labels
    k_mask<<<NROWS / 256, 256, 0, stream>>>(edge_tokens, mask_rows, labels, MTOK);

    // embeddings
    k_embed<<<(NNODES * FDIM) / 256, 256, 0, stream>>>(node_tokens, emb, X, NNODES * FDIM);
    k_embed<<<(NEDGES * FDIM) / 256, 256, 0, stream>>>(MTOK, emb, E_, NEDGES * FDIM);

    // msg = relu(e @ W_msg + x[src]); scatter-add to agg[dst]
    gemm_kernel<<<dim3(NEDGES / 64, FDIM / 64), 256, 0, stream>>>(
        E_, W_msg, nullptr, X, src, dst, AGG, NEDGES, FDIM, FDIM, 1);

    // h = relu(x @ W_node + agg)   (in-place into AGG)
    gemm_kernel<<<dim3(NNODES / 64, FDIM / 64), 256, 0, stream>>>(
        X, W_node, nullptr, AGG, nullptr, nullptr, AGG, NNODES, FDIM, FDIM, 1);

    // eh = h[src] + h[dst]
    k_eh<<<(NEDGES * FDIM) / 256, 256, 0, stream>>>(AGG, src, dst, EH);

    // z1 = eh @ lc1_w + lc1_b    ([16384,64] @ [64,256])
    gemm_kernel<<<dim3(NROWS / 64, DGPT / 64), 256, 0, stream>>>(
        EH, lc1_w, lc1_b, nullptr, nullptr, nullptr, Z1, NROWS, DGPT, DIM, 0);

    // q,k,v projections
    gemm_kernel<<<dim3(NROWS / 64, DGPT / 64), 256, 0, stream>>>(
        Z1, Wq, nullptr, nullptr, nullptr, nullptr, Q_, NROWS, DGPT, DGPT, 0);
    gemm_kernel<<<dim3(NROWS / 64, DGPT / 64), 256, 0, stream>>>(
        Z1, Wk, nullptr, nullptr, nullptr, nullptr, K_, NROWS, DGPT, DGPT, 0);
    gemm_kernel<<<dim3(NROWS / 64, DGPT / 64), 256, 0, stream>>>(
        Z1, Wv, nullptr, nullptr, nullptr, nullptr, Vv, NROWS, DGPT, DGPT, 0);

    // attention
    k_attn<<<NEDGES, 256, 0, stream>>>(Q_, K_, Vv, O_);

    // x2 = z1 + o @ Wo
    gemm_kernel<<<dim3(NROWS / 64, DGPT / 64), 256, 0, stream>>>(
        O_, Wo, nullptr, Z1, nullptr, nullptr, X2, NROWS, DGPT, DGPT, 0);

    // u = gelu(x2 @ Wf1)
    gemm_kernel<<<dim3(NROWS / 64, (4 * DGPT) / 64), 256, 0, stream>>>(
        X2, Wf1, nullptr, nullptr, nullptr, nullptr, U_, NROWS, 4 * DGPT, DGPT, 2);

    // y2 = x2 + u @ Wf2
    gemm_kernel<<<dim3(NROWS / 64, DGPT / 64), 256, 0, stream>>>(
        U_, Wf2, nullptr, X2, nullptr, nullptr, Y2, NROWS, DGPT, 4 * DGPT, 0);

    // y = y2 @ lc2_w + lc2_b
    gemm_kernel<<<dim3(NROWS / 64, DIM / 64), 256, 0, stream>>>(
        Y2, lc2_w, lc2_b, nullptr, nullptr, nullptr, Y_, NROWS, DIM, DGPT, 0);

    // probs = softmax(y @ emb^T)
    k_lmhead<<<NROWS / 16, 256, 0, stream>>>(Y_, emb, probs);
}